// Round 4
// baseline (230.297 us; speedup 1.0000x reference)
//
#include <hip/hip_runtime.h>
#include <hip/hip_cooperative_groups.h>

namespace cg = cooperative_groups;

// Problem constants
#define B_DIM 8
#define F_DIM 16384
#define K_DIM 3
#define M_DIM 64
#define MCH   16                 // m per block
#define FCH   512                // f per block (two 256 sub-chunks)
#define LOG2E 1.4426950408889634f
#define QOFF  (M_DIM * 256)      // ws: [m*256 + b*32 + fc] sums, +QOFF sumsqs

// ---------------------------------------------------------------------------
// Fused cooperative kernel.
// grid = 1024 (b(8) x mc(4) x fc(32)), block = 256, 16 waves/CU co-resident
// (VGPR capped at 128 by __launch_bounds__(256,4): 512/SIMD / 4 waves).
// Phase 1: feat in REGISTERS (m-loop fully unrolled -> static indices; the
//          R2 `#pragma unroll 2` left fA[m]/fB[m] runtime-indexed -> scratch,
//          which was the 137us regression).
// grid.sync()
// Phase 2: reduce partials -> A,C per channel; BN+ReLU; single output write.
// ---------------------------------------------------------------------------
__global__ __launch_bounds__(256, 4) void fkc_fused_kernel(
    const float* __restrict__ normals,   // [B,3,F]
    const float* __restrict__ walpha,    // [M*4]
    const float* __restrict__ wbeta,     // [M*4]
    const float* __restrict__ gamma,     // [M]
    const float* __restrict__ beta,      // [M]
    const int*   __restrict__ nidx,      // [B,F,K]
    float* __restrict__ out,             // [B,M,F]
    float* __restrict__ ws)
{
    __shared__ float4 sW[MCH * 4];
    __shared__ float sPS[MCH][4], sPQ[MCH][4];
    __shared__ float sA[MCH], sC[MCH];

    const int tid = threadIdx.x;
    const int b   = blockIdx.x >> 7;         // 128 blocks per batch
    const int mc  = (blockIdx.x >> 5) & 3;   // m-chunk
    const int fc  = blockIdx.x & 31;         // f-chunk (512 f each)

    // ---- kernel-point table for this block's 16 m's ----
    // ||p||^2 == 1 (unit normals): arg_log2 = 25*log2e*dot - 12.5*log2e*(1+||w||^2)
    if (tid < MCH * 4) {
        int idx = mc * MCH * 4 + tid;
        float a = walpha[idx], bb = wbeta[idx];
        float sa = sinf(a), ca = cosf(a);
        float sb = sinf(bb), cb = cosf(bb);
        float wx = sa * cb, wy = sa * sb, wz = ca;
        float w2 = wx * wx + wy * wy + wz * wz;
        sW[tid] = make_float4(wx * 25.0f * LOG2E, wy * 25.0f * LOG2E,
                              wz * 25.0f * LOG2E, -12.5f * LOG2E * (w2 + 1.0f));
    }
    __syncthreads();

    // ---- load two point-sets (f and f+256) ----
    const int fA0 = fc * FCH + tid;
    const int fB0 = fA0 + 256;
    const float* nb = normals + (size_t)b * 3 * F_DIM;
    float pxA[4], pyA[4], pzA[4], pxB[4], pyB[4], pzB[4];
    pxA[0] = nb[fA0]; pyA[0] = nb[F_DIM + fA0]; pzA[0] = nb[2 * F_DIM + fA0];
    pxB[0] = nb[fB0]; pyB[0] = nb[F_DIM + fB0]; pzB[0] = nb[2 * F_DIM + fB0];
    {
        const int* ia  = nidx + ((size_t)b * F_DIM + fA0) * K_DIM;
        const int* ibn = nidx + ((size_t)b * F_DIM + fB0) * K_DIM;
#pragma unroll
        for (int k = 0; k < K_DIM; ++k) {
            int id = ia[k];
            pxA[k + 1] = nb[id]; pyA[k + 1] = nb[F_DIM + id]; pzA[k + 1] = nb[2 * F_DIM + id];
            id = ibn[k];
            pxB[k + 1] = nb[id]; pyB[k + 1] = nb[F_DIM + id]; pzB[k + 1] = nb[2 * F_DIM + id];
        }
    }

    // ---- phase 1: feat in registers (FULL unroll -> static array indices) ----
    float fA[MCH], fB[MCH];
#pragma unroll
    for (int m = 0; m < MCH; ++m) {
        float a0 = 0.f, a1 = 0.f, a2 = 0.f, a3 = 0.f;
        float b0 = 0.f, b1 = 0.f, b2 = 0.f, b3 = 0.f;
#pragma unroll
        for (int j = 0; j < 4; ++j) {
            float4 w = sW[m * 4 + j];
            a0 += __builtin_amdgcn_exp2f(fmaf(w.x, pxA[0], fmaf(w.y, pyA[0], fmaf(w.z, pzA[0], w.w))));
            a1 += __builtin_amdgcn_exp2f(fmaf(w.x, pxA[1], fmaf(w.y, pyA[1], fmaf(w.z, pzA[1], w.w))));
            a2 += __builtin_amdgcn_exp2f(fmaf(w.x, pxA[2], fmaf(w.y, pyA[2], fmaf(w.z, pzA[2], w.w))));
            a3 += __builtin_amdgcn_exp2f(fmaf(w.x, pxA[3], fmaf(w.y, pyA[3], fmaf(w.z, pzA[3], w.w))));
            b0 += __builtin_amdgcn_exp2f(fmaf(w.x, pxB[0], fmaf(w.y, pyB[0], fmaf(w.z, pzB[0], w.w))));
            b1 += __builtin_amdgcn_exp2f(fmaf(w.x, pxB[1], fmaf(w.y, pyB[1], fmaf(w.z, pzB[1], w.w))));
            b2 += __builtin_amdgcn_exp2f(fmaf(w.x, pxB[2], fmaf(w.y, pyB[2], fmaf(w.z, pzB[2], w.w))));
            b3 += __builtin_amdgcn_exp2f(fmaf(w.x, pxB[3], fmaf(w.y, pyB[3], fmaf(w.z, pzB[3], w.w))));
        }
        fA[m] = ((a0 + a1) + (a2 + a3)) * (1.0f / 16.0f);
        fB[m] = ((b0 + b1) + (b2 + b3)) * (1.0f / 16.0f);
    }

    // ---- per-block deterministic partials (no atomics, no zeroing) ----
    const int wave = tid >> 6, lane = tid & 63;
#pragma unroll
    for (int m = 0; m < MCH; ++m) {
        float s = fA[m] + fB[m];
        float q = fA[m] * fA[m] + fB[m] * fB[m];
#pragma unroll
        for (int off = 32; off >= 1; off >>= 1) {
            s += __shfl_xor(s, off, 64);
            q += __shfl_xor(q, off, 64);
        }
        if (lane == 0) { sPS[m][wave] = s; sPQ[m][wave] = q; }
    }
    __syncthreads();
    if (tid < MCH) {
        float s = (sPS[tid][0] + sPS[tid][1]) + (sPS[tid][2] + sPS[tid][3]);
        float q = (sPQ[tid][0] + sPQ[tid][1]) + (sPQ[tid][2] + sPQ[tid][3]);
        int slot = (mc * MCH + tid) * 256 + b * 32 + fc;
        ws[slot] = s;
        ws[QOFF + slot] = q;
    }

    cg::this_grid().sync();

    // ---- phase 2: stats (16 threads per m), then BN+ReLU write ----
    {
        const int ml = tid >> 4, sub = tid & 15;
        const int mg = mc * MCH + ml;
        float s = 0.f, q = 0.f;
#pragma unroll
        for (int i = 0; i < 16; ++i) {
            int idx = mg * 256 + sub * 16 + i;
            s += ws[idx];
            q += ws[QOFF + idx];
        }
#pragma unroll
        for (int off = 8; off >= 1; off >>= 1) {
            s += __shfl_xor(s, off, 64);
            q += __shfl_xor(q, off, 64);
        }
        if (sub == 0) {
            const float invcnt = 1.0f / (float)(B_DIM * F_DIM);
            float mean = s * invcnt;
            float var  = q * invcnt - mean * mean;
            float inv  = rsqrtf(var + 1e-5f);
            float A = gamma[mg] * inv;
            sA[ml] = A;
            sC[ml] = beta[mg] - mean * A;
        }
    }
    __syncthreads();

    float* ob = out + ((size_t)b * M_DIM + mc * MCH) * F_DIM + fc * FCH + tid;
#pragma unroll
    for (int m = 0; m < MCH; ++m) {
        float A = sA[m], C = sC[m];
        ob[(size_t)m * F_DIM]       = fmaxf(fmaf(fA[m], A, C), 0.0f);
        ob[(size_t)m * F_DIM + 256] = fmaxf(fmaf(fB[m], A, C), 0.0f);
    }
}

// ===========================================================================
// Fallback path (only used if cooperative launch is rejected)
// ===========================================================================
__global__ void fkc_zero_kernel(float* __restrict__ ws)
{
    if (threadIdx.x < 2 * M_DIM) ws[threadIdx.x] = 0.0f;
}

__global__ __launch_bounds__(256) void fkc_feat_kernel(
    const float* __restrict__ normals, const float* __restrict__ walpha,
    const float* __restrict__ wbeta, const int* __restrict__ nidx,
    float* __restrict__ feat_out)
{
    __shared__ float4 sW[MCH * 4];
    const int tid = threadIdx.x;
    const int b  = blockIdx.x >> 8;
    const int mc = (blockIdx.x >> 6) & 3;
    const int fc = blockIdx.x & 63;
    if (tid < MCH * 4) {
        int idx = mc * MCH * 4 + tid;
        float a = walpha[idx], bb = wbeta[idx];
        float sa = sinf(a), ca = cosf(a);
        float sb = sinf(bb), cb = cosf(bb);
        float wx = sa * cb, wy = sa * sb, wz = ca;
        float w2 = wx * wx + wy * wy + wz * wz;
        sW[tid] = make_float4(wx * 25.0f * LOG2E, wy * 25.0f * LOG2E,
                              wz * 25.0f * LOG2E, -12.5f * LOG2E * (w2 + 1.0f));
    }
    __syncthreads();
    const int f = (fc << 8) + tid;
    const float* nb = normals + (size_t)b * 3 * F_DIM;
    float px[4], py[4], pz[4];
    px[0] = nb[f]; py[0] = nb[F_DIM + f]; pz[0] = nb[2 * F_DIM + f];
    const int* ib = nidx + ((size_t)b * F_DIM + f) * K_DIM;
#pragma unroll
    for (int k = 0; k < K_DIM; ++k) {
        int id = ib[k];
        px[k + 1] = nb[id]; py[k + 1] = nb[F_DIM + id]; pz[k + 1] = nb[2 * F_DIM + id];
    }
    float* outb = feat_out + ((size_t)b * M_DIM + mc * MCH) * F_DIM + f;
#pragma unroll 2
    for (int m = 0; m < MCH; ++m) {
        float s0 = 0.f, s1 = 0.f, s2 = 0.f, s3 = 0.f;
#pragma unroll
        for (int j = 0; j < 4; ++j) {
            float4 w = sW[m * 4 + j];
            s0 += __builtin_amdgcn_exp2f(fmaf(w.x, px[0], fmaf(w.y, py[0], fmaf(w.z, pz[0], w.w))));
            s1 += __builtin_amdgcn_exp2f(fmaf(w.x, px[1], fmaf(w.y, py[1], fmaf(w.z, pz[1], w.w))));
            s2 += __builtin_amdgcn_exp2f(fmaf(w.x, px[2], fmaf(w.y, py[2], fmaf(w.z, pz[2], w.w))));
            s3 += __builtin_amdgcn_exp2f(fmaf(w.x, px[3], fmaf(w.y, py[3], fmaf(w.z, pz[3], w.w))));
        }
        outb[(size_t)m * F_DIM] = ((s0 + s1) + (s2 + s3)) * (1.0f / 16.0f);
    }
}

__global__ __launch_bounds__(256) void fkc_sum_kernel(const float* __restrict__ feat,
                                                      float* __restrict__ ws)
{
    __shared__ float sS[4], sQ[4];
    const int row = blockIdx.x;
    const int m = row & 63;
    const int tid = threadIdx.x;
    const float4* p4 = (const float4*)(feat + (size_t)row * F_DIM);
    float s = 0.f, q = 0.f;
#pragma unroll
    for (int i = 0; i < 16; ++i) {
        float4 v = p4[tid + i * 256];
        s += (v.x + v.y) + (v.z + v.w);
        q += (v.x * v.x + v.y * v.y) + (v.z * v.z + v.w * v.w);
    }
#pragma unroll
    for (int off = 32; off >= 1; off >>= 1) {
        s += __shfl_xor(s, off, 64);
        q += __shfl_xor(q, off, 64);
    }
    const int wave = tid >> 6, lane = tid & 63;
    if (lane == 0) { sS[wave] = s; sQ[wave] = q; }
    __syncthreads();
    if (tid == 0) {
        atomicAdd(ws + m,         (sS[0] + sS[1]) + (sS[2] + sS[3]));
        atomicAdd(ws + M_DIM + m, (sQ[0] + sQ[1]) + (sQ[2] + sQ[3]));
    }
}

__global__ void fkc_stats_kernel(const float* __restrict__ gamma,
                                 const float* __restrict__ beta,
                                 float* __restrict__ ws)
{
    int m = threadIdx.x;
    if (m < M_DIM) {
        const float invcnt = 1.0f / (float)(B_DIM * F_DIM);
        float mean = ws[m] * invcnt;
        float var  = ws[M_DIM + m] * invcnt - mean * mean;
        float inv  = rsqrtf(var + 1e-5f);
        float A = gamma[m] * inv;
        ws[2 * M_DIM + m] = A;
        ws[3 * M_DIM + m] = beta[m] - mean * A;
    }
}

__global__ __launch_bounds__(256) void fkc_bn_kernel(float* __restrict__ out,
                                                     const float* __restrict__ ws)
{
    size_t i4 = (size_t)blockIdx.x * blockDim.x + threadIdx.x;
    int m = (int)((i4 >> 12) & 63);
    float A = ws[2 * M_DIM + m];
    float C = ws[3 * M_DIM + m];
    float4 v = reinterpret_cast<float4*>(out)[i4];
    v.x = fmaxf(fmaf(v.x, A, C), 0.0f);
    v.y = fmaxf(fmaf(v.y, A, C), 0.0f);
    v.z = fmaxf(fmaf(v.z, A, C), 0.0f);
    v.w = fmaxf(fmaf(v.w, A, C), 0.0f);
    reinterpret_cast<float4*>(out)[i4] = v;
}

// ---------------------------------------------------------------------------
extern "C" void kernel_launch(void* const* d_in, const int* in_sizes, int n_in,
                              void* d_out, int out_size, void* d_ws, size_t ws_size,
                              hipStream_t stream)
{
    const float* normals = (const float*)d_in[0];
    const float* walpha  = (const float*)d_in[1];
    const float* wbeta   = (const float*)d_in[2];
    const float* gamma   = (const float*)d_in[3];
    const float* beta    = (const float*)d_in[4];
    const int*   nidx    = (const int*)d_in[5];
    float* out = (float*)d_out;
    float* ws  = (float*)d_ws;

    void* args[] = { (void*)&normals, (void*)&walpha, (void*)&wbeta,
                     (void*)&gamma, (void*)&beta, (void*)&nidx,
                     (void*)&out, (void*)&ws };
    hipError_t rc = hipLaunchCooperativeKernel((const void*)fkc_fused_kernel,
                                               dim3(1024), dim3(256),
                                               args, 0, stream);
    if (rc != hipSuccess) {
        // Fallback: 5-dispatch path, deterministic (zero-kernel + atomics).
        hipLaunchKernelGGL(fkc_zero_kernel, dim3(1), dim3(128), 0, stream, ws);
        hipLaunchKernelGGL(fkc_feat_kernel, dim3(2048), dim3(256), 0, stream,
                           normals, walpha, wbeta, nidx, out);
        hipLaunchKernelGGL(fkc_sum_kernel, dim3(B_DIM * M_DIM), dim3(256), 0, stream,
                           out, ws);
        hipLaunchKernelGGL(fkc_stats_kernel, dim3(1), dim3(64), 0, stream,
                           gamma, beta, ws);
        hipLaunchKernelGGL(fkc_bn_kernel, dim3(8192), dim3(256), 0, stream,
                           out, ws);
    }
}

// Round 5
// 153.916 us; speedup vs baseline: 1.4962x; 1.4962x over previous
//
#include <hip/hip_runtime.h>
#include <hip/hip_cooperative_groups.h>

namespace cg = cooperative_groups;

// Problem constants
#define B_DIM 8
#define F_DIM 16384
#define K_DIM 3
#define M_DIM 64
#define MCH   16                 // m per block
#define FCH   512                // f per block (two 256 sub-chunks)
#define LOG2E 1.4426950408889634f
#define QOFF  (M_DIM * 256)      // ws: [m*256 + b*32 + fc] sums, +QOFF sumsqs

// ---------------------------------------------------------------------------
// Fused cooperative kernel, v2: NO feat liveness across grid.sync().
// R2/R3 lesson: keeping 32 feat values in registers across the sync made the
// allocator spill them to scratch (R3: 94/196 MB FETCH/WRITE vs 7.6/33.8
// ideal). Here phase 1 streams pre-BN feat straight to `out` (no register
// arrays at all), phase 2 re-reads it through L2/L3 (32 MB, ~5us) for BN+ReLU.
// grid = 1024 (b(8) x mc(4) x fc(32)), block = 256, 4 blocks/CU co-resident.
// ---------------------------------------------------------------------------
__global__ __launch_bounds__(256, 4) void fkc_fused_kernel(
    const float* __restrict__ normals,   // [B,3,F]
    const float* __restrict__ walpha,    // [M*4]
    const float* __restrict__ wbeta,     // [M*4]
    const float* __restrict__ gamma,     // [M]
    const float* __restrict__ beta,      // [M]
    const int*   __restrict__ nidx,      // [B,F,K]
    float* __restrict__ out,             // [B,M,F]
    float* __restrict__ ws)
{
    __shared__ float4 sW[MCH * 4];
    __shared__ float sPS[MCH][4], sPQ[MCH][4];
    __shared__ float sA[MCH], sC[MCH];

    const int tid = threadIdx.x;
    const int b   = blockIdx.x >> 7;         // 128 blocks per batch
    const int mc  = (blockIdx.x >> 5) & 3;   // m-chunk
    const int fc  = blockIdx.x & 31;         // f-chunk (512 f each)

    // ---- kernel-point table for this block's 16 m's ----
    // ||p||^2 == 1 (unit normals): arg_log2 = 25*log2e*dot - 12.5*log2e*(1+||w||^2)
    if (tid < MCH * 4) {
        int idx = mc * MCH * 4 + tid;
        float a = walpha[idx], bb = wbeta[idx];
        float sa = sinf(a), ca = cosf(a);
        float sb = sinf(bb), cb = cosf(bb);
        float wx = sa * cb, wy = sa * sb, wz = ca;
        float w2 = wx * wx + wy * wy + wz * wz;
        sW[tid] = make_float4(wx * 25.0f * LOG2E, wy * 25.0f * LOG2E,
                              wz * 25.0f * LOG2E, -12.5f * LOG2E * (w2 + 1.0f));
    }
    __syncthreads();

    // ---- load two point-sets (f and f+256) ----
    const int fA0 = fc * FCH + tid;
    const int fB0 = fA0 + 256;
    const float* nb = normals + (size_t)b * 3 * F_DIM;
    float pxA[4], pyA[4], pzA[4], pxB[4], pyB[4], pzB[4];
    pxA[0] = nb[fA0]; pyA[0] = nb[F_DIM + fA0]; pzA[0] = nb[2 * F_DIM + fA0];
    pxB[0] = nb[fB0]; pyB[0] = nb[F_DIM + fB0]; pzB[0] = nb[2 * F_DIM + fB0];
    {
        const int* ia  = nidx + ((size_t)b * F_DIM + fA0) * K_DIM;
        const int* ibn = nidx + ((size_t)b * F_DIM + fB0) * K_DIM;
#pragma unroll
        for (int k = 0; k < K_DIM; ++k) {
            int id = ia[k];
            pxA[k + 1] = nb[id]; pyA[k + 1] = nb[F_DIM + id]; pzA[k + 1] = nb[2 * F_DIM + id];
            id = ibn[k];
            pxB[k + 1] = nb[id]; pyB[k + 1] = nb[F_DIM + id]; pzB[k + 1] = nb[2 * F_DIM + id];
        }
    }

    // ---- phase 1: compute feat, store immediately, partials via butterfly.
    //      No register arrays: per-m values die within the iteration. ----
    const int wave = tid >> 6, lane = tid & 63;
    float* ob = out + ((size_t)b * M_DIM + mc * MCH) * F_DIM + fc * FCH + tid;
#pragma unroll 2
    for (int m = 0; m < MCH; ++m) {
        float a0 = 0.f, a1 = 0.f, a2 = 0.f, a3 = 0.f;
        float b0 = 0.f, b1 = 0.f, b2 = 0.f, b3 = 0.f;
#pragma unroll
        for (int j = 0; j < 4; ++j) {
            float4 w = sW[m * 4 + j];
            a0 += __builtin_amdgcn_exp2f(fmaf(w.x, pxA[0], fmaf(w.y, pyA[0], fmaf(w.z, pzA[0], w.w))));
            a1 += __builtin_amdgcn_exp2f(fmaf(w.x, pxA[1], fmaf(w.y, pyA[1], fmaf(w.z, pzA[1], w.w))));
            a2 += __builtin_amdgcn_exp2f(fmaf(w.x, pxA[2], fmaf(w.y, pyA[2], fmaf(w.z, pzA[2], w.w))));
            a3 += __builtin_amdgcn_exp2f(fmaf(w.x, pxA[3], fmaf(w.y, pyA[3], fmaf(w.z, pzA[3], w.w))));
            b0 += __builtin_amdgcn_exp2f(fmaf(w.x, pxB[0], fmaf(w.y, pyB[0], fmaf(w.z, pzB[0], w.w))));
            b1 += __builtin_amdgcn_exp2f(fmaf(w.x, pxB[1], fmaf(w.y, pyB[1], fmaf(w.z, pzB[1], w.w))));
            b2 += __builtin_amdgcn_exp2f(fmaf(w.x, pxB[2], fmaf(w.y, pyB[2], fmaf(w.z, pzB[2], w.w))));
            b3 += __builtin_amdgcn_exp2f(fmaf(w.x, pxB[3], fmaf(w.y, pyB[3], fmaf(w.z, pzB[3], w.w))));
        }
        float fA = ((a0 + a1) + (a2 + a3)) * (1.0f / 16.0f);
        float fB = ((b0 + b1) + (b2 + b3)) * (1.0f / 16.0f);
        ob[(size_t)m * F_DIM]       = fA;   // pre-BN feat -> global (re-read in ph2)
        ob[(size_t)m * F_DIM + 256] = fB;

        float s = fA + fB;
        float q = fA * fA + fB * fB;
#pragma unroll
        for (int off = 32; off >= 1; off >>= 1) {
            s += __shfl_xor(s, off, 64);
            q += __shfl_xor(q, off, 64);
        }
        if (lane == 0) { sPS[m][wave] = s; sPQ[m][wave] = q; }
    }
    __syncthreads();
    if (tid < MCH) {
        float s = (sPS[tid][0] + sPS[tid][1]) + (sPS[tid][2] + sPS[tid][3]);
        float q = (sPQ[tid][0] + sPQ[tid][1]) + (sPQ[tid][2] + sPQ[tid][3]);
        int slot = (mc * MCH + tid) * 256 + b * 32 + fc;
        ws[slot] = s;
        ws[QOFF + slot] = q;
    }

    cg::this_grid().sync();

    // ---- phase 2a: stats (16 threads per m) ----
    {
        const int ml = tid >> 4, sub = tid & 15;
        const int mg = mc * MCH + ml;
        float s = 0.f, q = 0.f;
#pragma unroll
        for (int i = 0; i < 16; ++i) {
            int idx = mg * 256 + sub * 16 + i;
            s += ws[idx];
            q += ws[QOFF + idx];
        }
#pragma unroll
        for (int off = 8; off >= 1; off >>= 1) {
            s += __shfl_xor(s, off, 64);
            q += __shfl_xor(q, off, 64);
        }
        if (sub == 0) {
            const float invcnt = 1.0f / (float)(B_DIM * F_DIM);
            float mean = s * invcnt;
            float var  = q * invcnt - mean * mean;
            float inv  = rsqrtf(var + 1e-5f);
            float A = gamma[mg] * inv;
            sA[ml] = A;
            sC[ml] = beta[mg] - mean * A;
        }
    }
    __syncthreads();

    // ---- phase 2b: BN+ReLU over this block's own 128 KB of out (L2/L3 hot).
    //      2 m-rows per iteration: 256 threads = 2 x 128 float4. ----
    {
        float4* base4 = (float4*)(out + ((size_t)b * M_DIM + mc * MCH) * F_DIM + fc * FCH);
        const int mrow = tid >> 7;            // 0..1
        const int col  = tid & 127;           // 0..127 float4s
        const size_t rowpitch4 = F_DIM / 4;   // float4 per m row
#pragma unroll
        for (int it = 0; it < 8; ++it) {
            int m = it * 2 + mrow;
            float A = sA[m], C = sC[m];
            float4* p = base4 + (size_t)m * rowpitch4 + col;
            float4 v = *p;
            v.x = fmaxf(fmaf(v.x, A, C), 0.0f);
            v.y = fmaxf(fmaf(v.y, A, C), 0.0f);
            v.z = fmaxf(fmaf(v.z, A, C), 0.0f);
            v.w = fmaxf(fmaf(v.w, A, C), 0.0f);
            *p = v;
        }
    }
}

// ===========================================================================
// Fallback path (only used if cooperative launch is rejected)
// ===========================================================================
__global__ void fkc_zero_kernel(float* __restrict__ ws)
{
    if (threadIdx.x < 2 * M_DIM) ws[threadIdx.x] = 0.0f;
}

__global__ __launch_bounds__(256) void fkc_feat_kernel(
    const float* __restrict__ normals, const float* __restrict__ walpha,
    const float* __restrict__ wbeta, const int* __restrict__ nidx,
    float* __restrict__ feat_out)
{
    __shared__ float4 sW[MCH * 4];
    const int tid = threadIdx.x;
    const int b  = blockIdx.x >> 8;
    const int mc = (blockIdx.x >> 6) & 3;
    const int fc = blockIdx.x & 63;
    if (tid < MCH * 4) {
        int idx = mc * MCH * 4 + tid;
        float a = walpha[idx], bb = wbeta[idx];
        float sa = sinf(a), ca = cosf(a);
        float sb = sinf(bb), cb = cosf(bb);
        float wx = sa * cb, wy = sa * sb, wz = ca;
        float w2 = wx * wx + wy * wy + wz * wz;
        sW[tid] = make_float4(wx * 25.0f * LOG2E, wy * 25.0f * LOG2E,
                              wz * 25.0f * LOG2E, -12.5f * LOG2E * (w2 + 1.0f));
    }
    __syncthreads();
    const int f = (fc << 8) + tid;
    const float* nb = normals + (size_t)b * 3 * F_DIM;
    float px[4], py[4], pz[4];
    px[0] = nb[f]; py[0] = nb[F_DIM + f]; pz[0] = nb[2 * F_DIM + f];
    const int* ib = nidx + ((size_t)b * F_DIM + f) * K_DIM;
#pragma unroll
    for (int k = 0; k < K_DIM; ++k) {
        int id = ib[k];
        px[k + 1] = nb[id]; py[k + 1] = nb[F_DIM + id]; pz[k + 1] = nb[2 * F_DIM + id];
    }
    float* outb = feat_out + ((size_t)b * M_DIM + mc * MCH) * F_DIM + f;
#pragma unroll 2
    for (int m = 0; m < MCH; ++m) {
        float s0 = 0.f, s1 = 0.f, s2 = 0.f, s3 = 0.f;
#pragma unroll
        for (int j = 0; j < 4; ++j) {
            float4 w = sW[m * 4 + j];
            s0 += __builtin_amdgcn_exp2f(fmaf(w.x, px[0], fmaf(w.y, py[0], fmaf(w.z, pz[0], w.w))));
            s1 += __builtin_amdgcn_exp2f(fmaf(w.x, px[1], fmaf(w.y, py[1], fmaf(w.z, pz[1], w.w))));
            s2 += __builtin_amdgcn_exp2f(fmaf(w.x, px[2], fmaf(w.y, py[2], fmaf(w.z, pz[2], w.w))));
            s3 += __builtin_amdgcn_exp2f(fmaf(w.x, px[3], fmaf(w.y, py[3], fmaf(w.z, pz[3], w.w))));
        }
        outb[(size_t)m * F_DIM] = ((s0 + s1) + (s2 + s3)) * (1.0f / 16.0f);
    }
}

__global__ __launch_bounds__(256) void fkc_sum_kernel(const float* __restrict__ feat,
                                                      float* __restrict__ ws)
{
    __shared__ float sS[4], sQ[4];
    const int row = blockIdx.x;
    const int m = row & 63;
    const int tid = threadIdx.x;
    const float4* p4 = (const float4*)(feat + (size_t)row * F_DIM);
    float s = 0.f, q = 0.f;
#pragma unroll
    for (int i = 0; i < 16; ++i) {
        float4 v = p4[tid + i * 256];
        s += (v.x + v.y) + (v.z + v.w);
        q += (v.x * v.x + v.y * v.y) + (v.z * v.z + v.w * v.w);
    }
#pragma unroll
    for (int off = 32; off >= 1; off >>= 1) {
        s += __shfl_xor(s, off, 64);
        q += __shfl_xor(q, off, 64);
    }
    const int wave = tid >> 6, lane = tid & 63;
    if (lane == 0) { sS[wave] = s; sQ[wave] = q; }
    __syncthreads();
    if (tid == 0) {
        atomicAdd(ws + m,         (sS[0] + sS[1]) + (sS[2] + sS[3]));
        atomicAdd(ws + M_DIM + m, (sQ[0] + sQ[1]) + (sQ[2] + sQ[3]));
    }
}

__global__ void fkc_stats_kernel(const float* __restrict__ gamma,
                                 const float* __restrict__ beta,
                                 float* __restrict__ ws)
{
    int m = threadIdx.x;
    if (m < M_DIM) {
        const float invcnt = 1.0f / (float)(B_DIM * F_DIM);
        float mean = ws[m] * invcnt;
        float var  = ws[M_DIM + m] * invcnt - mean * mean;
        float inv  = rsqrtf(var + 1e-5f);
        float A = gamma[m] * inv;
        ws[2 * M_DIM + m] = A;
        ws[3 * M_DIM + m] = beta[m] - mean * A;
    }
}

__global__ __launch_bounds__(256) void fkc_bn_kernel(float* __restrict__ out,
                                                     const float* __restrict__ ws)
{
    size_t i4 = (size_t)blockIdx.x * blockDim.x + threadIdx.x;
    int m = (int)((i4 >> 12) & 63);
    float A = ws[2 * M_DIM + m];
    float C = ws[3 * M_DIM + m];
    float4 v = reinterpret_cast<float4*>(out)[i4];
    v.x = fmaxf(fmaf(v.x, A, C), 0.0f);
    v.y = fmaxf(fmaf(v.y, A, C), 0.0f);
    v.z = fmaxf(fmaf(v.z, A, C), 0.0f);
    v.w = fmaxf(fmaf(v.w, A, C), 0.0f);
    reinterpret_cast<float4*>(out)[i4] = v;
}

// ---------------------------------------------------------------------------
extern "C" void kernel_launch(void* const* d_in, const int* in_sizes, int n_in,
                              void* d_out, int out_size, void* d_ws, size_t ws_size,
                              hipStream_t stream)
{
    const float* normals = (const float*)d_in[0];
    const float* walpha  = (const float*)d_in[1];
    const float* wbeta   = (const float*)d_in[2];
    const float* gamma   = (const float*)d_in[3];
    const float* beta    = (const float*)d_in[4];
    const int*   nidx    = (const int*)d_in[5];
    float* out = (float*)d_out;
    float* ws  = (float*)d_ws;

    void* args[] = { (void*)&normals, (void*)&walpha, (void*)&wbeta,
                     (void*)&gamma, (void*)&beta, (void*)&nidx,
                     (void*)&out, (void*)&ws };
    hipError_t rc = hipLaunchCooperativeKernel((const void*)fkc_fused_kernel,
                                               dim3(1024), dim3(256),
                                               args, 0, stream);
    if (rc != hipSuccess) {
        // Fallback: 5-dispatch path, deterministic (zero-kernel + atomics).
        hipLaunchKernelGGL(fkc_zero_kernel, dim3(1), dim3(128), 0, stream, ws);
        hipLaunchKernelGGL(fkc_feat_kernel, dim3(2048), dim3(256), 0, stream,
                           normals, walpha, wbeta, nidx, out);
        hipLaunchKernelGGL(fkc_sum_kernel, dim3(B_DIM * M_DIM), dim3(256), 0, stream,
                           out, ws);
        hipLaunchKernelGGL(fkc_stats_kernel, dim3(1), dim3(64), 0, stream,
                           gamma, beta, ws);
        hipLaunchKernelGGL(fkc_bn_kernel, dim3(8192), dim3(256), 0, stream,
                           out, ws);
    }
}

// Round 6
// 55.937 us; speedup vs baseline: 4.1170x; 2.7516x over previous
//
#include <hip/hip_runtime.h>

// Problem constants (from reference setup_inputs)
#define B_DIM 8
#define F_DIM 16384
#define K_DIM 3
#define M_DIM 64
#define MCH   16                 // m-values per block in feat kernel
#define LOG2E 1.4426950408889634f

// ws float layout (all deterministic, fully overwritten every launch):
//   [0,512)    : per-(m,b) partial sums   slot = m*8+b
//   [512,1024) : per-(m,b) partial sumsq  slot = 512 + m*8+b
//   [1024,1088): A = gamma*invstd
//   [1088,1152): C = beta - mean*A
#define WS_S 0
#define WS_Q 512
#define WS_A 1024
#define WS_C 1088

// ---------------------------------------------------------------------------
// Kernel 1: feat[b,m,f] (pre-BN) into d_out. Pure compute, no reductions.
// grid = 2048 (8 b * 4 mchunk * 64 fchunk), block = 256 -> 32 waves/CU.
// ---------------------------------------------------------------------------
__global__ __launch_bounds__(256) void fkc_feat_kernel(
    const float* __restrict__ normals,   // [B,3,F]
    const float* __restrict__ walpha,    // [M*4]
    const float* __restrict__ wbeta,     // [M*4]
    const int*   __restrict__ nidx,      // [B,F,K] int32
    float* __restrict__ feat_out)        // [B,M,F]
{
    __shared__ float4 sW[MCH * 4];
    const int tid = threadIdx.x;
    const int b  = blockIdx.x >> 8;          // 256 blocks per batch
    const int mc = (blockIdx.x >> 6) & 3;    // m-chunk
    const int fc = blockIdx.x & 63;          // f-chunk

    // Kernel-point table. ||p||^2 == 1 (unit normals), folded into .w:
    // arg_log2 = 25*log2e*dot - 12.5*log2e*(1 + ||w||^2)
    if (tid < MCH * 4) {
        int idx = mc * MCH * 4 + tid;
        float a = walpha[idx], bb = wbeta[idx];
        float sa = sinf(a), ca = cosf(a);
        float sb = sinf(bb), cb = cosf(bb);
        float wx = sa * cb, wy = sa * sb, wz = ca;
        float w2 = wx * wx + wy * wy + wz * wz;
        sW[tid] = make_float4(wx * 25.0f * LOG2E, wy * 25.0f * LOG2E,
                              wz * 25.0f * LOG2E, -12.5f * LOG2E * (w2 + 1.0f));
    }
    __syncthreads();

    const int f = (fc << 8) + tid;           // coalesced f
    const float* nb = normals + (size_t)b * 3 * F_DIM;
    float px[4], py[4], pz[4];
    px[0] = nb[f]; py[0] = nb[F_DIM + f]; pz[0] = nb[2 * F_DIM + f];
    const int* ib = nidx + ((size_t)b * F_DIM + f) * K_DIM;
#pragma unroll
    for (int k = 0; k < K_DIM; ++k) {
        int id = ib[k];
        px[k + 1] = nb[id]; py[k + 1] = nb[F_DIM + id]; pz[k + 1] = nb[2 * F_DIM + id];
    }

    float* outb = feat_out + ((size_t)b * M_DIM + mc * MCH) * F_DIM + f;
#pragma unroll 2
    for (int m = 0; m < MCH; ++m) {
        float s0 = 0.f, s1 = 0.f, s2 = 0.f, s3 = 0.f;
#pragma unroll
        for (int j = 0; j < 4; ++j) {
            float4 w = sW[m * 4 + j];
            s0 += __builtin_amdgcn_exp2f(fmaf(w.x, px[0], fmaf(w.y, py[0], fmaf(w.z, pz[0], w.w))));
            s1 += __builtin_amdgcn_exp2f(fmaf(w.x, px[1], fmaf(w.y, py[1], fmaf(w.z, pz[1], w.w))));
            s2 += __builtin_amdgcn_exp2f(fmaf(w.x, px[2], fmaf(w.y, py[2], fmaf(w.z, pz[2], w.w))));
            s3 += __builtin_amdgcn_exp2f(fmaf(w.x, px[3], fmaf(w.y, py[3], fmaf(w.z, pz[3], w.w))));
        }
        outb[(size_t)m * F_DIM] = ((s0 + s1) + (s2 + s3)) * (1.0f / 16.0f);
    }
}

// ---------------------------------------------------------------------------
// Kernel 2: per-(b,m) row sum/sumsq over feat (L2/L3-hot re-read).
// grid = B*M = 512 blocks, one row of 16384 floats each.
// DETERMINISTIC: block writes its own slot. No atomics, no zeroing needed.
// ---------------------------------------------------------------------------
__global__ __launch_bounds__(256) void fkc_sum_kernel(const float* __restrict__ feat,
                                                      float* __restrict__ ws)
{
    __shared__ float sS[4], sQ[4];
    const int row = blockIdx.x;              // b*64 + m  (feat layout [B,M,F])
    const int b = row >> 6, m = row & 63;
    const int tid = threadIdx.x;
    const float4* p4 = (const float4*)(feat + (size_t)row * F_DIM);

    float s = 0.f, q = 0.f;
#pragma unroll
    for (int i = 0; i < 16; ++i) {           // 4096 float4 / 256 threads
        float4 v = p4[tid + i * 256];
        s += (v.x + v.y) + (v.z + v.w);
        q += (v.x * v.x + v.y * v.y) + (v.z * v.z + v.w * v.w);
    }
#pragma unroll
    for (int off = 32; off >= 1; off >>= 1) {
        s += __shfl_xor(s, off, 64);
        q += __shfl_xor(q, off, 64);
    }
    const int wave = tid >> 6, lane = tid & 63;
    if (lane == 0) { sS[wave] = s; sQ[wave] = q; }
    __syncthreads();
    if (tid == 0) {
        ws[WS_S + m * 8 + b] = (sS[0] + sS[1]) + (sS[2] + sS[3]);
        ws[WS_Q + m * 8 + b] = (sQ[0] + sQ[1]) + (sQ[2] + sQ[3]);
    }
}

// ---------------------------------------------------------------------------
// Kernel 3: fold 8 b-partials per channel, produce A,C. 1 block x 64 threads.
// ---------------------------------------------------------------------------
__global__ void fkc_stats_kernel(const float* __restrict__ gamma,
                                 const float* __restrict__ beta,
                                 float* __restrict__ ws)
{
    int m = threadIdx.x;
    if (m < M_DIM) {
        float s = 0.f, q = 0.f;
#pragma unroll
        for (int b = 0; b < B_DIM; ++b) {
            s += ws[WS_S + m * 8 + b];
            q += ws[WS_Q + m * 8 + b];
        }
        const float invcnt = 1.0f / (float)(B_DIM * F_DIM);
        float mean = s * invcnt;
        float var  = q * invcnt - mean * mean;
        float inv  = rsqrtf(var + 1e-5f);
        float A = gamma[m] * inv;
        ws[WS_A + m] = A;
        ws[WS_C + m] = beta[m] - mean * A;
    }
}

// ---------------------------------------------------------------------------
// Kernel 4: in-place BN + ReLU over d_out, float4-vectorized.
// total float4 = B*M*F/4 = 2097152 ; grid = 8192 x 256
// ---------------------------------------------------------------------------
__global__ __launch_bounds__(256) void fkc_bn_kernel(float* __restrict__ out,
                                                     const float* __restrict__ ws)
{
    size_t i4 = (size_t)blockIdx.x * blockDim.x + threadIdx.x;
    int m = (int)((i4 >> 12) & 63);          // (i4*4 / F) % M, F=16384
    float A = ws[WS_A + m];
    float C = ws[WS_C + m];
    float4 v = reinterpret_cast<float4*>(out)[i4];
    v.x = fmaxf(fmaf(v.x, A, C), 0.0f);
    v.y = fmaxf(fmaf(v.y, A, C), 0.0f);
    v.z = fmaxf(fmaf(v.z, A, C), 0.0f);
    v.w = fmaxf(fmaf(v.w, A, C), 0.0f);
    reinterpret_cast<float4*>(out)[i4] = v;
}

// ---------------------------------------------------------------------------
extern "C" void kernel_launch(void* const* d_in, const int* in_sizes, int n_in,
                              void* d_out, int out_size, void* d_ws, size_t ws_size,
                              hipStream_t stream)
{
    const float* normals = (const float*)d_in[0];
    const float* walpha  = (const float*)d_in[1];
    const float* wbeta   = (const float*)d_in[2];
    const float* gamma   = (const float*)d_in[3];
    const float* beta    = (const float*)d_in[4];
    const int*   nidx    = (const int*)d_in[5];
    float* out = (float*)d_out;
    float* ws  = (float*)d_ws;

    // No memset, no atomics: every ws slot used is overwritten every launch.
    hipLaunchKernelGGL(fkc_feat_kernel, dim3(2048), dim3(256), 0, stream,
                       normals, walpha, wbeta, nidx, out);
    hipLaunchKernelGGL(fkc_sum_kernel, dim3(B_DIM * M_DIM), dim3(256), 0, stream,
                       out, ws);
    hipLaunchKernelGGL(fkc_stats_kernel, dim3(1), dim3(64), 0, stream,
                       gamma, beta, ws);
    hipLaunchKernelGGL(fkc_bn_kernel, dim3(8192), dim3(256), 0, stream,
                       out, ws);
}

// Round 7
// 50.855 us; speedup vs baseline: 4.5285x; 1.0999x over previous
//
#include <hip/hip_runtime.h>

// Problem constants (from reference setup_inputs)
#define B_DIM 8
#define F_DIM 16384
#define K_DIM 3
#define M_DIM 64
#define MCH   16                 // m-values per block in feat kernel
#define LOG2E 1.4426950408889634f

// ws float layout (deterministic, fully overwritten every launch):
//   [0, 32768)     : partial sums   slot = m*512 + b*64 + fc
//   [32768, 65536) : partial sumsq  (same indexing)
// Each partial = sum over one block's 256 f-values for channel m.
#define WS_Q 32768

// ---------------------------------------------------------------------------
// Kernel 1: feat[b,m,f] (pre-BN) -> d_out, plus per-(m,b,fc) partial
// sum/sumsq -> ws. grid = 2048 (8 b * 4 mc * 64 fc), block = 256.
// Reduction strategy: 3-step xor butterfly (offs 8/16/32) -> per-(lane&7)
// class sums; lanes 0-7 bank them in LDS; one fold after the loop.
// Half the shuffle count of the full 6-step that hurt in R0.
// ---------------------------------------------------------------------------
__global__ __launch_bounds__(256) void fkc_feat_kernel(
    const float* __restrict__ normals,   // [B,3,F]
    const float* __restrict__ walpha,    // [M*4]
    const float* __restrict__ wbeta,     // [M*4]
    const int*   __restrict__ nidx,      // [B,F,K] int32
    float* __restrict__ feat_out,        // [B,M,F]
    float* __restrict__ ws)
{
    __shared__ float4 sW[MCH * 4];
    __shared__ float sRS[MCH][32];       // [m][wave*8 + class]
    __shared__ float sRQ[MCH][32];

    const int tid = threadIdx.x;
    const int b  = blockIdx.x >> 8;          // 256 blocks per batch
    const int mc = (blockIdx.x >> 6) & 3;    // m-chunk
    const int fc = blockIdx.x & 63;          // f-chunk

    // Kernel-point table. ||p||^2 == 1 (unit normals), folded into .w:
    // arg_log2 = 25*log2e*dot - 12.5*log2e*(1 + ||w||^2)
    if (tid < MCH * 4) {
        int idx = mc * MCH * 4 + tid;
        float a = walpha[idx], bb = wbeta[idx];
        float sa = sinf(a), ca = cosf(a);
        float sb = sinf(bb), cb = cosf(bb);
        float wx = sa * cb, wy = sa * sb, wz = ca;
        float w2 = wx * wx + wy * wy + wz * wz;
        sW[tid] = make_float4(wx * 25.0f * LOG2E, wy * 25.0f * LOG2E,
                              wz * 25.0f * LOG2E, -12.5f * LOG2E * (w2 + 1.0f));
    }
    __syncthreads();

    const int f = (fc << 8) + tid;           // coalesced f
    const float* nb = normals + (size_t)b * 3 * F_DIM;
    float px[4], py[4], pz[4];
    px[0] = nb[f]; py[0] = nb[F_DIM + f]; pz[0] = nb[2 * F_DIM + f];
    const int* ib = nidx + ((size_t)b * F_DIM + f) * K_DIM;
#pragma unroll
    for (int k = 0; k < K_DIM; ++k) {
        int id = ib[k];
        px[k + 1] = nb[id]; py[k + 1] = nb[F_DIM + id]; pz[k + 1] = nb[2 * F_DIM + id];
    }

    const int wave = tid >> 6, lane = tid & 63;
    float* outb = feat_out + ((size_t)b * M_DIM + mc * MCH) * F_DIM + f;
#pragma unroll 2
    for (int m = 0; m < MCH; ++m) {
        float s0 = 0.f, s1 = 0.f, s2 = 0.f, s3 = 0.f;
#pragma unroll
        for (int j = 0; j < 4; ++j) {
            float4 w = sW[m * 4 + j];
            s0 += __builtin_amdgcn_exp2f(fmaf(w.x, px[0], fmaf(w.y, py[0], fmaf(w.z, pz[0], w.w))));
            s1 += __builtin_amdgcn_exp2f(fmaf(w.x, px[1], fmaf(w.y, py[1], fmaf(w.z, pz[1], w.w))));
            s2 += __builtin_amdgcn_exp2f(fmaf(w.x, px[2], fmaf(w.y, py[2], fmaf(w.z, pz[2], w.w))));
            s3 += __builtin_amdgcn_exp2f(fmaf(w.x, px[3], fmaf(w.y, py[3], fmaf(w.z, pz[3], w.w))));
        }
        float fv = ((s0 + s1) + (s2 + s3)) * (1.0f / 16.0f);
        outb[(size_t)m * F_DIM] = fv;

        // 3-step butterfly: every lane ends with the sum over its (lane&7)
        // class (8 lanes). Lanes 0-7 hold the 8 distinct class sums.
        float s = fv, q = fv * fv;
        s += __shfl_xor(s, 8, 64);  q += __shfl_xor(q, 8, 64);
        s += __shfl_xor(s, 16, 64); q += __shfl_xor(q, 16, 64);
        s += __shfl_xor(s, 32, 64); q += __shfl_xor(q, 32, 64);
        if (lane < 8) { sRS[m][wave * 8 + lane] = s; sRQ[m][wave * 8 + lane] = q; }
    }
    __syncthreads();

    // Fold 32 class-sums per m: thread t -> (m = t>>4, j = t&15).
    {
        const int m = tid >> 4, j = tid & 15;
        float s = sRS[m][j] + sRS[m][j + 16];
        float q = sRQ[m][j] + sRQ[m][j + 16];
        s += __shfl_xor(s, 1, 64);  q += __shfl_xor(q, 1, 64);
        s += __shfl_xor(s, 2, 64);  q += __shfl_xor(q, 2, 64);
        s += __shfl_xor(s, 4, 64);  q += __shfl_xor(q, 4, 64);
        s += __shfl_xor(s, 8, 64);  q += __shfl_xor(q, 8, 64);
        if (j == 0) {
            int slot = (mc * MCH + m) * 512 + b * 64 + fc;
            ws[slot] = s;
            ws[WS_Q + slot] = q;
        }
    }
}

// ---------------------------------------------------------------------------
// Kernel 2: stats + BN + ReLU. grid = B*M = 512 blocks, one (b,m) row each.
// Phase A: fold this channel's 512 partials (2 KB, L2-hot; redundant per-b
// but trivially cheap) -> A, C.
// Phase B: stream the 64 KB row in place with float4.
// ---------------------------------------------------------------------------
__global__ __launch_bounds__(256) void fkc_bn_kernel(
    float* __restrict__ out,             // [B,M,F]
    const float* __restrict__ gamma,
    const float* __restrict__ beta,
    const float* __restrict__ ws)
{
    __shared__ float sS[4], sQ[4];
    __shared__ float sAC[2];
    const int row = blockIdx.x;              // b*64 + m
    const int m = row & 63;
    const int tid = threadIdx.x;
    const int wave = tid >> 6, lane = tid & 63;

    // Phase A: reduce 512 partials (each thread takes 2).
    {
        float s = ws[m * 512 + tid]         + ws[m * 512 + tid + 256];
        float q = ws[WS_Q + m * 512 + tid]  + ws[WS_Q + m * 512 + tid + 256];
#pragma unroll
        for (int off = 32; off >= 1; off >>= 1) {
            s += __shfl_xor(s, off, 64);
            q += __shfl_xor(q, off, 64);
        }
        if (lane == 0) { sS[wave] = s; sQ[wave] = q; }
    }
    __syncthreads();
    if (tid == 0) {
        float s = (sS[0] + sS[1]) + (sS[2] + sS[3]);
        float q = (sQ[0] + sQ[1]) + (sQ[2] + sQ[3]);
        const float invcnt = 1.0f / (float)(B_DIM * F_DIM);
        float mean = s * invcnt;
        float var  = q * invcnt - mean * mean;
        float inv  = rsqrtf(var + 1e-5f);
        float A = gamma[m] * inv;
        sAC[0] = A;
        sAC[1] = beta[m] - mean * A;
    }
    __syncthreads();

    // Phase B: BN + ReLU over this row, float4.
    const float A = sAC[0], C = sAC[1];
    float4* p4 = (float4*)(out + (size_t)row * F_DIM);
#pragma unroll
    for (int i = 0; i < 16; ++i) {           // 4096 float4 / 256 threads
        float4 v = p4[tid + i * 256];
        v.x = fmaxf(fmaf(v.x, A, C), 0.0f);
        v.y = fmaxf(fmaf(v.y, A, C), 0.0f);
        v.z = fmaxf(fmaf(v.z, A, C), 0.0f);
        v.w = fmaxf(fmaf(v.w, A, C), 0.0f);
        p4[tid + i * 256] = v;
    }
}

// ---------------------------------------------------------------------------
extern "C" void kernel_launch(void* const* d_in, const int* in_sizes, int n_in,
                              void* d_out, int out_size, void* d_ws, size_t ws_size,
                              hipStream_t stream)
{
    const float* normals = (const float*)d_in[0];
    const float* walpha  = (const float*)d_in[1];
    const float* wbeta   = (const float*)d_in[2];
    const float* gamma   = (const float*)d_in[3];
    const float* beta    = (const float*)d_in[4];
    const int*   nidx    = (const int*)d_in[5];
    float* out = (float*)d_out;
    float* ws  = (float*)d_ws;

    // 2 dispatches. No memset, no atomics: every ws slot used is
    // overwritten every launch (poison-safe).
    hipLaunchKernelGGL(fkc_feat_kernel, dim3(2048), dim3(256), 0, stream,
                       normals, walpha, wbeta, nidx, out, ws);
    hipLaunchKernelGGL(fkc_bn_kernel, dim3(B_DIM * M_DIM), dim3(256), 0, stream,
                       out, gamma, beta, ws);
}